// Round 4
// baseline (265.137 us; speedup 1.0000x reference)
//
#include <hip/hip_runtime.h>

#define N_NODES 10000
#define N_EDGES 320000
#define MPAD 10112   // 158 * 64
#define NBIN 10048
#define CAP 128      // fixed CSR row capacity (mean degree 32; >CAP is ~17 sigma)

// ---- fused1 block-range dispatch: edges FIRST (long pole), then gemm1 tiles,
// then weight-prep grid-stride blocks.
#define E1BLKS 313                  // 313*1024 = 320512 >= 320000 edges (128 thr, 8 iters)
#define G1BLKS 632                  // gemm1: 158 m-tiles x 4 n-tiles
#define WB0    (E1BLKS + G1BLKS)    // = 945
#define WBLKS  1536                 // weight blocks; 1536*128 = 196608 = wft pass
#define GRID1  (WB0 + WBLKS)        // = 2481
// weight item space (sub-item units), expensive first:
//   wft-sub 196608 | bf-sub 512 | w1t 65536 | w2t 65536 | wc1t 262144 | bias1 512
#define WPREP_TOT 590848L

typedef unsigned short u16;
typedef short bf16x8 __attribute__((ext_vector_type(8)));
typedef float f32x4 __attribute__((ext_vector_type(4)));

__device__ __forceinline__ u16 f2b(float f) {
  unsigned u = __builtin_bit_cast(unsigned, f);
  unsigned r = u + 0x7fffu + ((u >> 16) & 1u);
  return (u16)(r >> 16);
}
__device__ __forceinline__ unsigned pack2(float a, float b) {
  return (unsigned)f2b(a) | ((unsigned)f2b(b) << 16);
}
__device__ __forceinline__ float blo(unsigned u) { return __builtin_bit_cast(float, u << 16); }
__device__ __forceinline__ float bhi(unsigned u) { return __builtin_bit_cast(float, u & 0xffff0000u); }
__device__ __forceinline__ int4 cvt16(float4 a, float4 b) {
  int4 r;
  r.x = (int)pack2(a.x, a.y); r.y = (int)pack2(a.z, a.w);
  r.z = (int)pack2(b.x, b.y); r.w = (int)pack2(b.z, b.w);
  return r;
}
// stage 16 fp32 A elements -> 2 int4 of bf16
__device__ __forceinline__ void ldA(const float* a, int4& lo, int4& hi) {
  float4 f0 = *(const float4*)(a),     f1 = *(const float4*)(a + 4);
  float4 f2 = *(const float4*)(a + 8), f3 = *(const float4*)(a + 12);
  lo = cvt16(f0, f1); hi = cvt16(f2, f3);
}
// stage Bt[n][k0..k0+15] from fp32 row-major w[k][n] (stride-256 gather + cvt)
__device__ __forceinline__ void ldB(const float* w, int n, int k0, int4& lo, int4& hi) {
  const float* p = w + (size_t)k0 * 256 + n;
  lo.x = (int)pack2(p[0],    p[256]);  lo.y = (int)pack2(p[512],  p[768]);
  lo.z = (int)pack2(p[1024], p[1280]); lo.w = (int)pack2(p[1536], p[1792]);
  hi.x = (int)pack2(p[2048], p[2304]); hi.y = (int)pack2(p[2560], p[2816]);
  hi.z = (int)pack2(p[3072], p[3328]); hi.w = (int)pack2(p[3584], p[3840]);
}

// ---------------------------------------------------------- param struct ----
struct PP {
  const float *x; const int *ei;
  const float *w0, *w1, *w2, *fcw0, *injw0, *fcw1, *injw1, *outw;
  const float *fcb0, *injb0, *fcb1, *injb1, *alpha, *outb, *b0;
  u16 *w1t, *w2t, *wc1t, *wft, *tmp;
  float *bias1, *bf;
  int *cursor, *deg; u16 *csr;
};

// ------------------------------------------------------------- fused1 -------
// R17: three prep-half restructures (R13/R15/R16) left prep at 45-48us ->
// the EDGE half (640K random device atomics ~ 14 G/s fabric ceiling) is the
// floor. So: hide MORE under it. fused1 = edge placement + gemm1 + all weight
// prep in ONE kernel. gemm1's w0t dependency is gone (B staged from fp32 w0,
// strided gather, L2-hot); its deg dependency is gone (deg_inv moved to
// aggregate-1). Edge blocks dispatch first. cursor/deg memset in-graph ->
// deterministic replays; pos<CAP guard -> no OOB ever.
__global__ __launch_bounds__(128, 4) void fused1(PP F) {
  const int tid = threadIdx.x, bid = blockIdx.x;
  __shared__ u16 As[64 * 72];
  __shared__ u16 Bs[64 * 72];

  if (bid < E1BLKS) {  // ---- edge placement + degree count (1024 edges/block)
    const int e0 = bid * 1024;
#pragma unroll
    for (int j = 0; j < 1024; j += 128) {
      int e = e0 + j + tid;
      if (e < N_EDGES) {
        int r = F.ei[e];
        int c = F.ei[N_EDGES + e];
        atomicAdd(&F.deg[c], 1);                       // reference deg = segsum(col)
        int pos = atomicAdd(&F.cursor[r], 1);
        if (pos < CAP) F.csr[r * CAP + pos] = (u16)c;  // guarded: no OOB ever
      }
    }
    return;
  }

  if (bid < WB0) {     // ---- gemm1 tile: tmp = relu(x @ w0 + b0), UNSCALED
    const int gb = bid - E1BLKS;
    const int m0 = (gb >> 2) * 64;
    const int n0 = (gb & 3) * 64;
    const int wave = tid >> 6, lane = tid & 63;
    const int wr = wave * 32, lm = lane & 15, koff = (lane >> 4) * 8;
    const int srow = tid >> 2, scol = (tid & 3) * 16;

    const int ar0 = min(m0 + srow, N_NODES - 1);       // never over-read x
    const int ar1 = min(m0 + srow + 32, N_NODES - 1);
    const float* Af0 = F.x + (size_t)ar0 * 256 + scol;
    const float* Af1 = F.x + (size_t)ar1 * 256 + scol;
    const int bn0 = n0 + srow, bn1 = n0 + srow + 32;
    u16* Asw0 = &As[srow * 72 + scol];
    u16* Asw1 = &As[(srow + 32) * 72 + scol];
    u16* Bsw0 = &Bs[srow * 72 + scol];
    u16* Bsw1 = &Bs[(srow + 32) * 72 + scol];

    f32x4 acc[2][4] = {};
    int4 pa0, pa1, pa2, pa3, pb0, pb1, pb2, pb3;
    ldA(Af0, pa0, pa1); ldA(Af1, pa2, pa3);
    ldB(F.w0, bn0, scol, pb0, pb1); ldB(F.w0, bn1, scol, pb2, pb3);

#pragma unroll
    for (int kb = 0; kb < 256; kb += 64) {
      __syncthreads();
      *(int4*)Asw0 = pa0; *(int4*)(Asw0 + 8) = pa1;
      *(int4*)Asw1 = pa2; *(int4*)(Asw1 + 8) = pa3;
      *(int4*)Bsw0 = pb0; *(int4*)(Bsw0 + 8) = pb1;
      *(int4*)Bsw1 = pb2; *(int4*)(Bsw1 + 8) = pb3;
      __syncthreads();
      if (kb + 64 < 256) {
        ldA(Af0 + kb + 64, pa0, pa1); ldA(Af1 + kb + 64, pa2, pa3);
        ldB(F.w0, bn0, kb + 64 + scol, pb0, pb1);
        ldB(F.w0, bn1, kb + 64 + scol, pb2, pb3);
      }
#pragma unroll
      for (int ks = 0; ks < 2; ++ks) {
        bf16x8 af[2], bfr[4];
#pragma unroll
        for (int mi = 0; mi < 2; ++mi)
          af[mi] = *(const bf16x8*)&As[(wr + mi * 16 + lm) * 72 + ks * 32 + koff];
#pragma unroll
        for (int ni = 0; ni < 4; ++ni)
          bfr[ni] = *(const bf16x8*)&Bs[(ni * 16 + lm) * 72 + ks * 32 + koff];
#pragma unroll
        for (int mi = 0; mi < 2; ++mi)
#pragma unroll
          for (int ni = 0; ni < 4; ++ni)
            acc[mi][ni] = __builtin_amdgcn_mfma_f32_16x16x32_bf16(af[mi], bfr[ni], acc[mi][ni], 0, 0, 0);
      }
    }

    const int q4 = (lane >> 4) * 4;
#pragma unroll
    for (int mi = 0; mi < 2; ++mi) {
#pragma unroll
      for (int ni = 0; ni < 4; ++ni) {
        const int gc = n0 + ni * 16 + lm;
        const float bv = F.b0[gc];
#pragma unroll
        for (int r = 0; r < 4; ++r) {
          const int gr = m0 + wr + mi * 16 + q4 + r;
          F.tmp[(size_t)gr * 256 + gc] = f2b(fmaxf(acc[mi][ni][r] + bv, 0.f));
        }
      }
    }
    return;
  }

  // ---- weight prep, grid-stride (hidden under the edge atomic phase)
  const float alpha = F.alpha[0];
  const long stride = (long)WBLKS * 128;   // = 196608 = wft pass on pass 1
  for (long ii = (long)(bid - WB0) * 128 + tid; ii < WPREP_TOT; ii += stride) {
    long i = ii;
    if (i < 196608) {  // Wf^T [64 n][768 k] = (Wcat2 @ out_w)^T, 4 lanes/item
      int item = (int)(i >> 2), part = (int)i & 3;
      int n = item & 63, k = item >> 6;
      const float* fr = (k < 512) ? F.fcw1 + (size_t)k * 512
                                  : F.injw1 + (size_t)(k - 512) * 512;
      float a0 = 0.f, a1 = 0.f, a2 = 0.f, a3 = 0.f;
      const int j0 = part * 128;
#pragma unroll 4
      for (int j = j0; j < j0 + 128; j += 4) {
        float4 f = *(const float4*)(fr + j);
        a0 += f.x * F.outw[(j + 0) * 64 + n];
        a1 += f.y * F.outw[(j + 1) * 64 + n];
        a2 += f.z * F.outw[(j + 2) * 64 + n];
        a3 += f.w * F.outw[(j + 3) * 64 + n];
      }
      float acc = (a0 + a1) + (a2 + a3);
      acc += __shfl_xor(acc, 1, 64);
      acc += __shfl_xor(acc, 2, 64);
      if (part == 0) {
        if (k < 512) acc *= alpha;
        F.wft[n * 768 + k] = f2b(acc);
      }
      continue;
    }
    i -= 196608;
    if (i < 512) {     // bf = bias2 @ out_w + out_b, 8 lanes/item
      int item = (int)(i >> 3), part = (int)i & 7;
      float acc = 0.f;
      const int j0 = part * 64;
#pragma unroll 4
      for (int j = j0; j < j0 + 64; ++j)
        acc += (alpha * F.fcb1[j] + F.injb1[j]) * F.outw[j * 64 + item];
      acc += __shfl_xor(acc, 1, 64);
      acc += __shfl_xor(acc, 2, 64);
      acc += __shfl_xor(acc, 4, 64);
      if (part == 0) F.bf[item] = F.outb[item] + acc;
      continue;
    }
    i -= 512;
    if (i < 65536) { F.w1t[i] = f2b(F.w1[(i & 255) * 256 + (i >> 8)]); continue; }
    i -= 65536;
    if (i < 65536) { F.w2t[i] = f2b(F.w2[(i & 255) * 256 + (i >> 8)]); continue; }
    i -= 65536;
    if (i < 262144) {  // Wcat1^T [512 n][512 k]: k<256 -> alpha*fc_w0 ; else inj_w0
      int n = (int)(i >> 9), k = (int)(i & 511);
      float v = (k < 256) ? alpha * F.fcw0[k * 512 + n] : F.injw0[(k - 256) * 512 + n];
      F.wc1t[i] = f2b(v); continue;
    }
    i -= 262144;
    if (i < 512) { F.bias1[i] = alpha * F.fcb0[i] + F.injb0[i]; continue; }
  }
}

// ---------------------------------------------------------------- GEMM ------
// 64x64 tile, TWO waves per block (128 thr). Proven R7-R12 body. SCALE reads
// deg[] and divides inline. Used for MP layers 2,3 and FC1.
template<int K, bool RELU, bool SCALE, bool F32OUT>
__global__ __launch_bounds__(128) void gemm64(
    const u16* __restrict__ A, int lda,
    const u16* __restrict__ Bt,
    const float* __restrict__ bias,
    const int* __restrict__ deg,
    u16* __restrict__ Cb, float* __restrict__ Cf, int ldc)
{
  __shared__ u16 As[64 * 72];
  __shared__ u16 Bs[64 * 72];
  const int tid = threadIdx.x;
  const int m0 = blockIdx.x * 64;
  const int n0 = blockIdx.y * 64;
  const int wave = tid >> 6;
  const int lane = tid & 63;
  const int wr = wave * 32;
  const int lm = lane & 15;
  const int koff = (lane >> 4) * 8;

  const int srow = tid >> 2;
  const int scol = (tid & 3) * 16;
  const u16* Ag0 = A + (size_t)(m0 + srow) * lda + scol;
  const u16* Ag1 = A + (size_t)(m0 + srow + 32) * lda + scol;
  const u16* Bg0 = Bt + (size_t)(n0 + srow) * K + scol;
  const u16* Bg1 = Bt + (size_t)(n0 + srow + 32) * K + scol;
  u16* Asw0 = &As[srow * 72 + scol];
  u16* Asw1 = &As[(srow + 32) * 72 + scol];
  u16* Bsw0 = &Bs[srow * 72 + scol];
  u16* Bsw1 = &Bs[(srow + 32) * 72 + scol];

  f32x4 acc[2][4] = {};

  int4 pa0 = *(const int4*)(Ag0),     pa1 = *(const int4*)(Ag0 + 8);
  int4 pa2 = *(const int4*)(Ag1),     pa3 = *(const int4*)(Ag1 + 8);
  int4 pb0 = *(const int4*)(Bg0),     pb1 = *(const int4*)(Bg0 + 8);
  int4 pb2 = *(const int4*)(Bg1),     pb3 = *(const int4*)(Bg1 + 8);

#pragma unroll
  for (int kb = 0; kb < K; kb += 64) {
    __syncthreads();
    *(int4*)Asw0 = pa0; *(int4*)(Asw0 + 8) = pa1;
    *(int4*)Asw1 = pa2; *(int4*)(Asw1 + 8) = pa3;
    *(int4*)Bsw0 = pb0; *(int4*)(Bsw0 + 8) = pb1;
    *(int4*)Bsw1 = pb2; *(int4*)(Bsw1 + 8) = pb3;
    __syncthreads();
    if (kb + 64 < K) {
      pa0 = *(const int4*)(Ag0 + kb + 64); pa1 = *(const int4*)(Ag0 + kb + 72);
      pa2 = *(const int4*)(Ag1 + kb + 64); pa3 = *(const int4*)(Ag1 + kb + 72);
      pb0 = *(const int4*)(Bg0 + kb + 64); pb1 = *(const int4*)(Bg0 + kb + 72);
      pb2 = *(const int4*)(Bg1 + kb + 64); pb3 = *(const int4*)(Bg1 + kb + 72);
    }
#pragma unroll
    for (int ks = 0; ks < 2; ++ks) {
      bf16x8 af[2], bf[4];
#pragma unroll
      for (int mi = 0; mi < 2; ++mi)
        af[mi] = *(const bf16x8*)&As[(wr + mi * 16 + lm) * 72 + ks * 32 + koff];
#pragma unroll
      for (int ni = 0; ni < 4; ++ni)
        bf[ni] = *(const bf16x8*)&Bs[(ni * 16 + lm) * 72 + ks * 32 + koff];
#pragma unroll
      for (int mi = 0; mi < 2; ++mi)
#pragma unroll
        for (int ni = 0; ni < 4; ++ni)
          acc[mi][ni] = __builtin_amdgcn_mfma_f32_16x16x32_bf16(af[mi], bf[ni], acc[mi][ni], 0, 0, 0);
    }
  }

  const int q4 = (lane >> 4) * 4;
#pragma unroll
  for (int mi = 0; mi < 2; ++mi) {
#pragma unroll
    for (int ni = 0; ni < 4; ++ni) {
      const int gc = n0 + ni * 16 + lm;
      const float bv = bias[gc];
#pragma unroll
      for (int r = 0; r < 4; ++r) {
        const int gr = m0 + wr + mi * 16 + q4 + r;
        float v = acc[mi][ni][r] + bv;
        if (RELU) v = fmaxf(v, 0.f);
        if (SCALE) v *= 1.0f / fmaxf((float)deg[gr], 1.0f);
        if (F32OUT) {
          if (gr < N_NODES) Cf[(size_t)gr * ldc + gc] = v;
        } else {
          Cb[(size_t)gr * ldc + gc] = f2b(v);
        }
      }
    }
  }
}

// ----------------------------------------------------- fold GEMM (split A) --
// out = [relu1 | h3] @ Wf + bf. A columns 0..511 from relu1; 512..767 from
// cat1 cols 256..511 (h3). Per-segment pointer select is exact (kb mult 64).
__global__ __launch_bounds__(128) void gemm_fold(
    const u16* __restrict__ Ar,    // relu1, lda 512
    const u16* __restrict__ Ah,    // cat1 + 256 (h3 half), lda 512
    const u16* __restrict__ Bt,    // wft, K=768
    const float* __restrict__ bias,
    float* __restrict__ Cf)        // out, ldc 64
{
  const int K = 768;
  __shared__ u16 As[64 * 72];
  __shared__ u16 Bs[64 * 72];
  const int tid = threadIdx.x;
  const int m0 = blockIdx.x * 64;
  const int n0 = 0;
  const int wave = tid >> 6;
  const int lane = tid & 63;
  const int wr = wave * 32;
  const int lm = lane & 15;
  const int koff = (lane >> 4) * 8;

  const int srow = tid >> 2;
  const int scol = (tid & 3) * 16;
  const int ar0 = m0 + srow, ar1 = m0 + srow + 32;
  auto aptr = [&](int row, int col) -> const u16* {
    return (col < 512) ? Ar + (size_t)row * 512 + col
                       : Ah + (size_t)row * 512 + (col - 512);
  };
  const u16* Bg0 = Bt + (size_t)(n0 + srow) * K + scol;
  const u16* Bg1 = Bt + (size_t)(n0 + srow + 32) * K + scol;
  u16* Asw0 = &As[srow * 72 + scol];
  u16* Asw1 = &As[(srow + 32) * 72 + scol];
  u16* Bsw0 = &Bs[srow * 72 + scol];
  u16* Bsw1 = &Bs[(srow + 32) * 72 + scol];

  f32x4 acc[2][4] = {};

  int4 pa0 = *(const int4*)aptr(ar0, scol);
  int4 pa1 = *(const int4*)aptr(ar0, scol + 8);
  int4 pa2 = *(const int4*)aptr(ar1, scol);
  int4 pa3 = *(const int4*)aptr(ar1, scol + 8);
  int4 pb0 = *(const int4*)(Bg0), pb1 = *(const int4*)(Bg0 + 8);
  int4 pb2 = *(const int4*)(Bg1), pb3 = *(const int4*)(Bg1 + 8);

#pragma unroll
  for (int kb = 0; kb < K; kb += 64) {
    __syncthreads();
    *(int4*)Asw0 = pa0; *(int4*)(Asw0 + 8) = pa1;
    *(int4*)Asw1 = pa2; *(int4*)(Asw1 + 8) = pa3;
    *(int4*)Bsw0 = pb0; *(int4*)(Bsw0 + 8) = pb1;
    *(int4*)Bsw1 = pb2; *(int4*)(Bsw1 + 8) = pb3;
    __syncthreads();
    if (kb + 64 < K) {
      int c = kb + 64 + scol;
      pa0 = *(const int4*)aptr(ar0, c);
      pa1 = *(const int4*)aptr(ar0, c + 8);
      pa2 = *(const int4*)aptr(ar1, c);
      pa3 = *(const int4*)aptr(ar1, c + 8);
      pb0 = *(const int4*)(Bg0 + kb + 64); pb1 = *(const int4*)(Bg0 + kb + 72);
      pb2 = *(const int4*)(Bg1 + kb + 64); pb3 = *(const int4*)(Bg1 + kb + 72);
    }
#pragma unroll
    for (int ks = 0; ks < 2; ++ks) {
      bf16x8 af[2], bf[4];
#pragma unroll
      for (int mi = 0; mi < 2; ++mi)
        af[mi] = *(const bf16x8*)&As[(wr + mi * 16 + lm) * 72 + ks * 32 + koff];
#pragma unroll
      for (int ni = 0; ni < 4; ++ni)
        bf[ni] = *(const bf16x8*)&Bs[(ni * 16 + lm) * 72 + ks * 32 + koff];
#pragma unroll
      for (int mi = 0; mi < 2; ++mi)
#pragma unroll
        for (int ni = 0; ni < 4; ++ni)
          acc[mi][ni] = __builtin_amdgcn_mfma_f32_16x16x32_bf16(af[mi], bf[ni], acc[mi][ni], 0, 0, 0);
    }
  }

  const int q4 = (lane >> 4) * 4;
#pragma unroll
  for (int mi = 0; mi < 2; ++mi) {
#pragma unroll
    for (int ni = 0; ni < 4; ++ni) {
      const int gc = ni * 16 + lm;
      const float bv = bias[gc];
#pragma unroll
      for (int r = 0; r < 4; ++r) {
        const int gr = m0 + wr + mi * 16 + q4 + r;
        if (gr < N_NODES) Cf[(size_t)gr * 64 + gc] = acc[mi][ni][r] + bv;
      }
    }
  }
}

// ----------------------------------------------------------- aggregate ------
// R17: HALF-FEATURE passes (fh=0/1). Per pass the gather table is 2.6MB ->
// fits a per-XCD L2 (4MB); full 5.2MB thrashed it. Two sequential launches
// per aggregate keep the halves temporally separated (that's the point).
// One WAVE per node; half-wave per neighbor, uint2/lane (8B), 8 neighbors in
// flight; cross-half __shfl reduce. DSC: deg_inv applied per neighbor (moved
// out of gemm1 to break fused1's dependency; fp32 math, same formula).
template<bool DSC>
__global__ __launch_bounds__(256) void aggregate(
    const u16* __restrict__ tmp, const int* __restrict__ cnt,
    const u16* __restrict__ csr, const int* __restrict__ deg,
    u16* __restrict__ out0, u16* __restrict__ A1, int mode, int fh)
{
  const int wv = threadIdx.x >> 6;
  const int lane = threadIdx.x & 63;
  const int r = blockIdx.x * 4 + wv;          // grid = 2500 -> r in [0,10000)
  const int half = lane >> 5;
  const int q = lane & 31;
  int n = cnt[r]; if (n > CAP) n = CAP;
  const int beg = r * CAP, end = beg + n;
  const size_t feat = (size_t)fh * 256 + (size_t)q * 8;
  const char* tb = (const char*)tmp;

  float s0 = 0.f, s1 = 0.f, s2 = 0.f, s3 = 0.f;
  int i = beg;
  for (; i + 8 <= end; i += 8) {
    uint2 v[4]; float sc[4];
#pragma unroll
    for (int j = 0; j < 4; ++j) {
      int c = csr[i + 2 * j + half];
      v[j] = *(const uint2*)(tb + (size_t)c * 512 + feat);
      sc[j] = DSC ? 1.0f / fmaxf((float)deg[c], 1.0f) : 1.0f;
    }
#pragma unroll
    for (int j = 0; j < 4; ++j) {
      if (DSC) {
        s0 += sc[j] * blo(v[j].x); s1 += sc[j] * bhi(v[j].x);
        s2 += sc[j] * blo(v[j].y); s3 += sc[j] * bhi(v[j].y);
      } else {
        s0 += blo(v[j].x); s1 += bhi(v[j].x);
        s2 += blo(v[j].y); s3 += bhi(v[j].y);
      }
    }
  }
  for (; i < end; i += 2) {
    int id = i + half;
    if (id < end) {
      int c = csr[id];
      uint2 v = *(const uint2*)(tb + (size_t)c * 512 + feat);
      float sc = DSC ? 1.0f / fmaxf((float)deg[c], 1.0f) : 1.0f;
      s0 += sc * blo(v.x); s1 += sc * bhi(v.x);
      s2 += sc * blo(v.y); s3 += sc * bhi(v.y);
    }
  }
  const int src = lane ^ 32;
  s0 += __shfl(s0, src, 64); s1 += __shfl(s1, src, 64);
  s2 += __shfl(s2, src, 64); s3 += __shfl(s3, src, 64);

  if (half == 0) {
    uint2 pv;
    pv.x = pack2(s0, s1); pv.y = pack2(s2, s3);
    if (mode == 0) {
      *(uint2*)((char*)out0 + (size_t)r * 512 + feat) = pv;
    } else {
      uint2 pr;
      pr.x = pack2(fmaxf(s0, 0.f), fmaxf(s1, 0.f));
      pr.y = pack2(fmaxf(s2, 0.f), fmaxf(s3, 0.f));
      *(uint2*)((char*)A1 + (size_t)r * 1024 + feat) = pr;          // relu(h3)
      *(uint2*)((char*)A1 + (size_t)r * 1024 + 512 + feat) = pv;    // h3
    }
  }
}

// -------------------------------------------------------------- launch ------
extern "C" void kernel_launch(void* const* d_in, const int* in_sizes, int n_in,
                              void* d_out, int out_size, void* d_ws, size_t ws_size,
                              hipStream_t stream) {
  const int* ei = (const int*)d_in[1];   // int inputs arrive as int32

  char* p = (char*)d_ws;
  auto carve = [&](size_t bytes) -> void* {
    void* r = (void*)p;
    p += (bytes + 255) & ~(size_t)255;
    return r;
  };
  int*   deg     = (int*)carve(MPAD * 4);     // 40448 B (256-mult) — adjacent
  int*   cursor  = (int*)carve(NBIN * 4);     // 40192 B (256-mult) — to deg
  u16*   csr     = (u16*)carve((size_t)NBIN * CAP * 2);
  float* bias1   = (float*)carve(512 * 4);
  float* bf      = (float*)carve(64 * 4);
  u16* w1t   = (u16*)carve(65536 * 2);
  u16* w2t   = (u16*)carve(65536 * 2);
  u16* wc1t  = (u16*)carve(262144 * 2);
  u16* wft   = (u16*)carve(49152 * 2);
  u16* tmp   = (u16*)carve((size_t)MPAD * 256 * 2);
  u16* h     = (u16*)carve((size_t)MPAD * 256 * 2);
  u16* cat1  = (u16*)carve((size_t)MPAD * 512 * 2);   // [relu(h3)|h3], 1024B rows
  u16* relu1 = (u16*)carve((size_t)MPAD * 512 * 2);   // relu(FC1 out)

  PP pp;
  pp.x = (const float*)d_in[0];
  pp.ei = ei;
  pp.w0 = (const float*)d_in[2];
  pp.w1 = (const float*)d_in[4];
  pp.w2 = (const float*)d_in[6];
  pp.fcw0 = (const float*)d_in[8];
  pp.fcw1 = (const float*)d_in[10];
  pp.injw0 = (const float*)d_in[12];
  pp.injw1 = (const float*)d_in[14];
  pp.outw = (const float*)d_in[17];
  pp.fcb0 = (const float*)d_in[9];
  pp.injb0 = (const float*)d_in[13];
  pp.fcb1 = (const float*)d_in[11];
  pp.injb1 = (const float*)d_in[15];
  pp.alpha = (const float*)d_in[16];
  pp.outb = (const float*)d_in[18];
  pp.b0 = (const float*)d_in[3];
  pp.w1t = w1t; pp.w2t = w2t;
  pp.wc1t = wc1t; pp.wft = wft; pp.tmp = tmp;
  pp.bias1 = bias1; pp.bf = bf;
  pp.cursor = cursor; pp.deg = deg; pp.csr = csr;

  const float* mp_b1 = (const float*)d_in[5];
  const float* mp_b2 = (const float*)d_in[7];
  float* out = (float*)d_out;

  // deg (MPAD) + cursor (NBIN) are adjacent: one in-graph memset -> timed
  // replays reset atomic state deterministically.
  hipMemsetAsync(deg, 0, (size_t)(MPAD + NBIN) * 4, stream);
  // edges + ALL weight prep + gemm1 (tmp = relu(x@w0+b0), unscaled)
  fused1<<<GRID1, 128, 0, stream>>>(pp);

  dim3 gmp(MPAD / 64, 4), gfc(MPAD / 64, 8), go(MPAD / 64, 1);
  // MP layer 1 aggregate: h = sum deg_inv[c] * tmp[c]  (two half-feature passes)
  aggregate<true ><<<2500, 256, 0, stream>>>(tmp, cursor, csr, deg, h, nullptr, 0, 0);
  aggregate<true ><<<2500, 256, 0, stream>>>(tmp, cursor, csr, deg, h, nullptr, 0, 1);
  // MP layers 2,3: tmp = relu(h @ W + b) / deg ; h' = aggregate(tmp)
  gemm64<256, true, true, false><<<gmp, 128, 0, stream>>>(h, 256, w1t, mp_b1, deg, tmp, nullptr, 256);
  aggregate<false><<<2500, 256, 0, stream>>>(tmp, cursor, csr, nullptr, h, nullptr, 0, 0);
  aggregate<false><<<2500, 256, 0, stream>>>(tmp, cursor, csr, nullptr, h, nullptr, 0, 1);
  gemm64<256, true, true, false><<<gmp, 128, 0, stream>>>(h, 256, w2t, mp_b2, deg, tmp, nullptr, 256);
  aggregate<false><<<2500, 256, 0, stream>>>(tmp, cursor, csr, nullptr, nullptr, cat1, 1, 0);
  aggregate<false><<<2500, 256, 0, stream>>>(tmp, cursor, csr, nullptr, nullptr, cat1, 1, 1);
  // FC1 (+inj0 fused, K=512): cat1=[relu(h3)|h3] -> relu -> relu1 (dense)
  gemm64<512, true, false, false><<<gfc, 128, 0, stream>>>(cat1, 512, wc1t, bias1, nullptr, relu1, nullptr, 512);
  // FOLDED final: out = [relu1 | h3] @ (Wcat2 @ out_w) + bf, fp32 store
  gemm_fold<<<go, 128, 0, stream>>>(relu1, cat1 + 256, wft, bf, out);
}